// Round 11
// baseline (312.666 us; speedup 1.0000x reference)
//
#include <hip/hip_runtime.h>
#include <hip/hip_bf16.h>
#include <stdint.h>

#define NEXP 64
#define TTOK 32768
#define HID  1024
#define IMID 512
#define CAP  1024

typedef __bf16 bf16x8 __attribute__((ext_vector_type(8)));
typedef float  f32x4  __attribute__((ext_vector_type(4)));

static __device__ __forceinline__ unsigned int f2bf_u(float f) {
    __hip_bfloat16 h = __float2bfloat16(f);
    return (unsigned int)*reinterpret_cast<unsigned short*>(&h);
}
static __device__ __forceinline__ unsigned int pack2(float lo, float hi) {
    return f2bf_u(lo) | (f2bf_u(hi) << 16);
}
static __device__ __forceinline__ unsigned short f2bf_s(float f) {
    __hip_bfloat16 h = __float2bfloat16(f);
    return *reinterpret_cast<unsigned short*>(&h);
}

static __device__ __forceinline__ void gload16(const void* g, void* l) {
    __builtin_amdgcn_global_load_lds(
        (const __attribute__((address_space(1))) unsigned int*)g,
        (__attribute__((address_space(3))) unsigned int*)l,
        16, 0, 0);
}

// wave-parallel exclusive prefix: sum of tpe[i] for i < e
static __device__ __forceinline__ int expert_start(const int* tpe, int e, int lane) {
    int v = tpe[lane];
    int contrib = (lane < e) ? v : 0;
    #pragma unroll
    for (int off = 1; off < 64; off <<= 1)
        contrib += __shfl_xor(contrib, off, 64);
    return contrib;
}

// ---- shared 64x64 transpose-convert core ----
// Reads fp32 [k0..+64][n0..+64] from src (row stride 1024 floats), produces the
// bf16 transposed tile in LDS Tl32[64 n][36 u32] (col c holds k-pair 2c,2c+1,
// col index XOR'd by ((n&7)<<2)). Caller then maps n->np and stores.
static __device__ __forceinline__ void tile_transpose_ld(const float* __restrict__ src,
                                                         uint32_t (*Tl32)[36], int t) {
    const int kl = t >> 4;            // 0..15
    const int nl = (t & 15) * 4;
    const bool evenk = (kl & 1) == 0;
    #pragma unroll
    for (int p = 0; p < 4; ++p) {
        const int k = kl + p * 16;
        f32x4 v = *reinterpret_cast<const f32x4*>(src + (size_t)k * 1024 + nl);
        uint32_t a01 = pack2(v.x, v.y);      // bf16(n=nl)   | bf16(n=nl+1)<<16 (own k)
        uint32_t a23 = pack2(v.z, v.w);
        uint32_t pb01 = __shfl_xor((int)a01, 16, 64);   // partner k^1
        uint32_t pb23 = __shfl_xor((int)a23, 16, 64);
        if (evenk) {
            const int col = k >> 1;          // k even
            uint32_t w0 = (a01 & 0xFFFFu) | (pb01 << 16);
            uint32_t w1 = (a01 >> 16)     | (pb01 & 0xFFFF0000u);
            uint32_t w2 = (a23 & 0xFFFFu) | (pb23 << 16);
            uint32_t w3 = (a23 >> 16)     | (pb23 & 0xFFFF0000u);
            Tl32[nl + 0][col ^ (((nl + 0) & 7) << 2)] = w0;
            Tl32[nl + 1][col ^ (((nl + 1) & 7) << 2)] = w1;
            Tl32[nl + 2][col ^ (((nl + 2) & 7) << 2)] = w2;
            Tl32[nl + 3][col ^ (((nl + 3) & 7) << 2)] = w3;
        }
    }
}

// ================= merged conversion kernel (flat: 1 tile or 1 chunk / block)
// blocks [0, 16384): one 64x64 w13 transpose-convert tile each
// blocks [16384, 32768): one 2048-float x convert chunk each
__global__ __launch_bounds__(256)
void cvt_all_k(const float* __restrict__ x, unsigned short* __restrict__ xbf,
               const float* __restrict__ w13, unsigned short* __restrict__ w13p) {
    __shared__ uint32_t Tl32[64][36];
    const int bid = blockIdx.x;
    const int t   = threadIdx.x;

    if (bid < 16384) {
        const int n0 = (bid & 15) * 64;
        const int k0 = ((bid >> 4) & 15) * 64;
        const int e  = bid >> 8;
        const float* src = w13 + ((size_t)e << 20) + (size_t)k0 * 1024 + n0;
        tile_transpose_ld(src, Tl32, t);
        __syncthreads();
        const int nloc = t >> 2;
        const int c8   = (t & 3) * 8;
        const int xr   = (nloc & 7) << 2;
        const int n = n0 + nloc;
        const int icol = n & 511, isup = n >> 9;
        const int np = (icol >> 5) * 64 + isup * 32 + (icol & 31);
        uint4 r0 = *reinterpret_cast<const uint4*>(&Tl32[nloc][(c8)     ^ xr]);
        uint4 r1 = *reinterpret_cast<const uint4*>(&Tl32[nloc][(c8 + 4) ^ xr]);
        unsigned short* dst = w13p + ((size_t)e << 20) + (size_t)np * 1024 + k0 + (t & 3) * 16;
        *reinterpret_cast<uint4*>(dst)     = r0;
        *reinterpret_cast<uint4*>(dst + 8) = r1;
    } else {
        size_t i = ((size_t)(bid - 16384) * 256 + t) * 8;
        f32x4 a = *reinterpret_cast<const f32x4*>(x + i);
        f32x4 b = *reinterpret_cast<const f32x4*>(x + i + 4);
        uint4 o;
        o.x = pack2(a.x, a.y); o.y = pack2(a.z, a.w);
        o.z = pack2(b.x, b.y); o.w = pack2(b.z, b.w);
        *reinterpret_cast<uint4*>(xbf + i) = o;
    }
}

// one 64x64 transpose-convert tile of w2: fp32 [e][512k][1024n] -> bf16 [e][n][512k]
static __device__ __forceinline__ void w2_tile_cvt(const float* __restrict__ w2,
                                                   unsigned short* __restrict__ w2p,
                                                   int tile, int t, char* lds) {
    const int e  = tile >> 7;
    const int k0 = ((tile >> 4) & 7) * 64;
    const int n0 = (tile & 15) * 64;
    uint32_t (*Tl32)[36] = reinterpret_cast<uint32_t(*)[36]>(lds);   // 9216 B
    const float* src = w2 + (size_t)e * (IMID * HID) + (size_t)k0 * 1024 + n0;
    tile_transpose_ld(src, Tl32, t);
    __syncthreads();
    const int nloc = t >> 2;
    const int c8   = (t & 3) * 8;
    const int xr   = (nloc & 7) << 2;
    uint4 r0 = *reinterpret_cast<const uint4*>(&Tl32[nloc][(c8)     ^ xr]);
    uint4 r1 = *reinterpret_cast<const uint4*>(&Tl32[nloc][(c8 + 4) ^ xr]);
    unsigned short* dst = w2p + (size_t)e * (HID * IMID) + (size_t)(n0 + nloc) * IMID + k0 + (t & 3) * 16;
    *reinterpret_cast<uint4*>(dst)     = r0;
    *reinterpret_cast<uint4*>(dst + 8) = r1;
}

// ================= GEMM1: xbf[cnt,1024] x w13p -> SwiGLU -> hbuf bf16 [T,512]
// 128m x 256n' tile, BK=64, 4 waves (2x2), acc 4x8 per wave.
// All staging via global_load_lds, both-sides XOR swizzle.
// Blocks [2048, 10240) each convert ONE w2 tile.
__global__ __launch_bounds__(256, 2)
void gemm1(const unsigned short* __restrict__ xbf,
           const int* __restrict__ tpe,
           const unsigned short* __restrict__ w13p,
           unsigned short* __restrict__ hbuf,
           const float* __restrict__ w2,
           unsigned short* __restrict__ w2p) {
    __shared__ alignas(16) char lds[49152];
    const int bid = blockIdx.x;                  // 10240 blocks
    const int t = threadIdx.x, lane = t & 63, w = t >> 6;

    if (bid >= 2048) {
        w2_tile_cvt(w2, w2p, bid - 2048, t, lds);
        return;
    }

    const int work = (bid & 7) * 256 + (bid >> 3);
    const int e  = work >> 5;                    // 0..63
    const int nt = (work >> 3) & 3;              // 0..3 : 256 n'-rows
    const int mt = work & 7;                     // 0..7

    int cnt = tpe[e]; if (cnt > CAP) cnt = CAP;
    const int m0 = mt * 128;
    if (m0 >= cnt) return;
    const int start = expert_start(tpe, e, lane);

    char* As = lds;            // [128 m][64k] bf16, source-swizzled (16 KB)
    char* Bs = lds + 16384;    // [256 n'][64k] bf16, source-swizzled (32 KB)
    const int wr = w >> 1, wc = w & 1;
    const int r = lane & 15, q = lane >> 4;

    f32x4 acc[4][8];
    const f32x4 z4 = {0.f, 0.f, 0.f, 0.f};
    #pragma unroll
    for (int i = 0; i < 4; ++i)
        #pragma unroll
        for (int j = 0; j < 8; ++j) acc[i][j] = z4;

    const int swb = ((lane & 7) ^ (lane >> 3)) << 4;
    const char* aP = (const char*)xbf;   // 2048 B rows
    const char* bP = (const char*)w13p + ((size_t)e << 21) + ((size_t)nt << 19);

    for (int kt = 0; kt < 16; ++kt) {
        __syncthreads();
        const int kb = kt * 128;
        #pragma unroll
        for (int i = 0; i < 4; ++i) {
            const int srow = w * 32 + i * 8 + (lane >> 3);
            long ar = (long)start + m0 + srow;
            if (ar > TTOK - 1) ar = TTOK - 1;
            gload16(aP + ar * 2048 + kb + swb, As + w * 4096 + i * 1024);
        }
        #pragma unroll
        for (int i = 0; i < 8; ++i) {
            const int srow = w * 64 + i * 8 + (lane >> 3);
            gload16(bP + (size_t)srow * 2048 + kb + swb, Bs + w * 8192 + i * 1024);
        }
        __syncthreads();
        #pragma unroll
        for (int kk = 0; kk < 2; ++kk) {
            bf16x8 af[4], bf[8];
            #pragma unroll
            for (int fm = 0; fm < 4; ++fm) {
                int row = (wr << 6) + (fm << 4) + r;
                af[fm] = *reinterpret_cast<const bf16x8*>(
                    As + row * 128 + ((kk * 64 + q * 16) ^ ((row & 7) << 4)));
            }
            #pragma unroll
            for (int fn = 0; fn < 8; ++fn) {
                int row = (wc << 7) + (fn << 4) + r;
                bf[fn] = *reinterpret_cast<const bf16x8*>(
                    Bs + row * 128 + ((kk * 64 + q * 16) ^ ((row & 7) << 4)));
            }
            #pragma unroll
            for (int fm = 0; fm < 4; ++fm)
                #pragma unroll
                for (int fn = 0; fn < 8; ++fn)
                    acc[fm][fn] = __builtin_amdgcn_mfma_f32_16x16x32_bf16(
                        af[fm], bf[fn], acc[fm][fn], 0, 0, 0);
        }
    }

    // SwiGLU: np_global = nt*256 + wc*128 + fn*16 + r, fn = c2*4 + isup*2 + fp
    // icol = (nt*4 + wc*2 + c2)*32 + fp*16 + r
    #pragma unroll
    for (int fm = 0; fm < 4; ++fm) {
        int mb = m0 + (wr << 6) + (fm << 4) + (q << 2);
        #pragma unroll
        for (int c2 = 0; c2 < 2; ++c2) {
            #pragma unroll
            for (int fp = 0; fp < 2; ++fp) {
                f32x4 g = acc[fm][c2 * 4 + fp];
                f32x4 u = acc[fm][c2 * 4 + 2 + fp];
                int icol = (nt * 4 + wc * 2 + c2) * 32 + fp * 16 + r;
                #pragma unroll
                for (int v = 0; v < 4; ++v) {
                    if (mb + v < cnt) {
                        float gv = g[v];
                        float sv = (gv / (1.f + __expf(-gv))) * u[v];
                        hbuf[(size_t)(start + mb + v) * IMID + icol] = f2bf_s(sv);
                    }
                }
            }
        }
    }
}

// ================= GEMM2: hbuf[cnt,512] x w2p -> out fp32 [T,1024]
// 128m x 256n tile, BK=64, 4 waves (2x2), acc 4x8.
__global__ __launch_bounds__(256, 2)
void gemm2(const unsigned short* __restrict__ hbuf,
           const int* __restrict__ tpe,
           const unsigned short* __restrict__ w2p,
           float* __restrict__ out) {
    __shared__ alignas(16) char lds[49152];
    const int bid  = blockIdx.x;                 // 2048 blocks
    const int work = (bid & 7) * 256 + (bid >> 3);
    const int e  = work >> 5;
    const int nt = (work >> 3) & 3;              // out cols [nt*256, +256)
    const int mt = work & 7;

    const int t = threadIdx.x, lane = t & 63, w = t >> 6;
    int cnt = tpe[e]; if (cnt > CAP) cnt = CAP;
    const int m0 = mt * 128;
    if (m0 >= cnt) return;
    const int start = expert_start(tpe, e, lane);

    char* As = lds;            // [128 m][64k]  (16 KB)
    char* Bs = lds + 16384;    // [256 n][64k]  (32 KB)
    const int wr = w >> 1, wc = w & 1;
    const int r = lane & 15, q = lane >> 4;

    f32x4 acc[4][8];
    const f32x4 z4 = {0.f, 0.f, 0.f, 0.f};
    #pragma unroll
    for (int i = 0; i < 4; ++i)
        #pragma unroll
        for (int j = 0; j < 8; ++j) acc[i][j] = z4;

    const int swb = ((lane & 7) ^ (lane >> 3)) << 4;
    const char* aP = (const char*)hbuf;   // 1024 B rows
    const char* bP = (const char*)w2p + ((size_t)e << 20) + ((size_t)nt << 18);

    for (int kt = 0; kt < 8; ++kt) {
        __syncthreads();
        const int kb = kt * 128;
        #pragma unroll
        for (int i = 0; i < 4; ++i) {
            const int srow = w * 32 + i * 8 + (lane >> 3);
            long ar = (long)start + m0 + srow;
            if (ar > TTOK - 1) ar = TTOK - 1;
            gload16(aP + ar * 1024 + kb + swb, As + w * 4096 + i * 1024);
        }
        #pragma unroll
        for (int i = 0; i < 8; ++i) {
            const int srow = w * 64 + i * 8 + (lane >> 3);
            gload16(bP + (size_t)srow * 1024 + kb + swb, Bs + w * 8192 + i * 1024);
        }
        __syncthreads();
        #pragma unroll
        for (int kk = 0; kk < 2; ++kk) {
            bf16x8 af[4], bf[8];
            #pragma unroll
            for (int fm = 0; fm < 4; ++fm) {
                int row = (wr << 6) + (fm << 4) + r;
                af[fm] = *reinterpret_cast<const bf16x8*>(
                    As + row * 128 + ((kk * 64 + q * 16) ^ ((row & 7) << 4)));
            }
            #pragma unroll
            for (int fn = 0; fn < 8; ++fn) {
                int row = (wc << 7) + (fn << 4) + r;
                bf[fn] = *reinterpret_cast<const bf16x8*>(
                    Bs + row * 128 + ((kk * 64 + q * 16) ^ ((row & 7) << 4)));
            }
            #pragma unroll
            for (int fm = 0; fm < 4; ++fm)
                #pragma unroll
                for (int fn = 0; fn < 8; ++fn)
                    acc[fm][fn] = __builtin_amdgcn_mfma_f32_16x16x32_bf16(
                        af[fm], bf[fn], acc[fm][fn], 0, 0, 0);
        }
    }

    #pragma unroll
    for (int fm = 0; fm < 4; ++fm) {
        int mb = m0 + (wr << 6) + (fm << 4) + (q << 2);
        #pragma unroll
        for (int fn = 0; fn < 8; ++fn) {
            int ocol = (nt << 8) + (wc << 7) + (fn << 4) + r;
            #pragma unroll
            for (int v = 0; v < 4; ++v) {
                if (mb + v < cnt)
                    out[(size_t)(start + mb + v) * HID + ocol] = acc[fm][fn][v];
            }
        }
    }
}

extern "C" void kernel_launch(void* const* d_in, const int* in_sizes, int n_in,
                              void* d_out, int out_size, void* d_ws, size_t ws_size,
                              hipStream_t stream) {
    const float* x   = (const float*)d_in[0];
    const int*   tpe = (const int*)d_in[1];
    const float* w13 = (const float*)d_in[2];
    const float* w2  = (const float*)d_in[3];
    float* out = (float*)d_out;

    char* ws = (char*)d_ws;
    unsigned short* xbf  = (unsigned short*)(ws);                           // 67 MB
    unsigned short* hbuf = (unsigned short*)(ws + 67108864);                // 33.5 MB
    unsigned short* w13p = (unsigned short*)(ws + 67108864 + 33554432);     // 134 MB
    unsigned short* w2p  = (unsigned short*)(ws + 67108864 + 33554432 + 134217728); // 67 MB

    cvt_all_k<<<dim3(32768, 1, 1), dim3(256, 1, 1), 0, stream>>>(x, xbf, w13, w13p);
    gemm1    <<<dim3(10240, 1, 1), dim3(256, 1, 1), 0, stream>>>(xbf, tpe, w13p, hbuf, w2, w2p);
    gemm2    <<<dim3(2048, 1, 1), dim3(256, 1, 1), 0, stream>>>(hbuf, tpe, w2p, out);
}

// Round 12
// 285.441 us; speedup vs baseline: 1.0954x; 1.0954x over previous
//
#include <hip/hip_runtime.h>
#include <hip/hip_bf16.h>
#include <stdint.h>

#define NEXP 64
#define TTOK 32768
#define HID  1024
#define IMID 512
#define CAP  1024

typedef __bf16 bf16x8 __attribute__((ext_vector_type(8)));
typedef float  f32x4  __attribute__((ext_vector_type(4)));

static __device__ __forceinline__ unsigned int f2bf_u(float f) {
    __hip_bfloat16 h = __float2bfloat16(f);
    return (unsigned int)*reinterpret_cast<unsigned short*>(&h);
}
static __device__ __forceinline__ unsigned int pack2(float lo, float hi) {
    return f2bf_u(lo) | (f2bf_u(hi) << 16);
}
static __device__ __forceinline__ unsigned short f2bf_s(float f) {
    __hip_bfloat16 h = __float2bfloat16(f);
    return *reinterpret_cast<unsigned short*>(&h);
}

static __device__ __forceinline__ void gload16(const void* g, void* l) {
    __builtin_amdgcn_global_load_lds(
        (const __attribute__((address_space(1))) unsigned int*)g,
        (__attribute__((address_space(3))) unsigned int*)l,
        16, 0, 0);
}

// wave-parallel exclusive prefix: sum of tpe[i] for i < e
static __device__ __forceinline__ int expert_start(const int* tpe, int e, int lane) {
    int v = tpe[lane];
    int contrib = (lane < e) ? v : 0;
    #pragma unroll
    for (int off = 1; off < 64; off <<= 1)
        contrib += __shfl_xor(contrib, off, 64);
    return contrib;
}

// ---- R10-proven 64x64 transpose-convert bodies (u16 LDS tile, no shfl) ----

// w13: fp32 [e][1024k][1024n] -> bf16 [e][np][1024k], np pairing 32-col granular
static __device__ __forceinline__ void w13_tile_cvt(const float* __restrict__ w13,
                                                    unsigned short* __restrict__ w13p,
                                                    int e, int k0, int n0, int t, char* lds) {
    unsigned short (*Tl)[72] = reinterpret_cast<unsigned short(*)[72]>(lds);  // 9216 B
    const int kl = t >> 4, nl = (t & 15) * 4;
    const float* src = w13 + ((size_t)e << 20) + (size_t)k0 * 1024 + n0;
    #pragma unroll
    for (int p = 0; p < 4; ++p) {
        int k = kl + p * 16;
        f32x4 v = *reinterpret_cast<const f32x4*>(src + (size_t)k * 1024 + nl);
        uint2 wv; wv.x = pack2(v.x, v.y); wv.y = pack2(v.z, v.w);
        *reinterpret_cast<uint2*>(&Tl[k][nl]) = wv;
    }
    __syncthreads();
    const int nloc = t >> 2, kc = (t & 3) * 16;
    const int n = n0 + nloc;
    const int icol = n & 511, isup = n >> 9;
    const int np = (icol >> 5) * 64 + isup * 32 + (icol & 31);
    unsigned int v32[8];
    #pragma unroll
    for (int j = 0; j < 8; ++j)
        v32[j] = (unsigned int)Tl[kc + 2 * j][nloc] |
                 ((unsigned int)Tl[kc + 2 * j + 1][nloc] << 16);
    unsigned short* dst = w13p + ((size_t)e << 20) + (size_t)np * 1024 + k0 + kc;
    uint4 o0 = {v32[0], v32[1], v32[2], v32[3]};
    uint4 o1 = {v32[4], v32[5], v32[6], v32[7]};
    *reinterpret_cast<uint4*>(dst)     = o0;
    *reinterpret_cast<uint4*>(dst + 8) = o1;
}

// w2: fp32 [e][512k][1024n] -> bf16 [e][n][512k]
static __device__ __forceinline__ void w2_tile_cvt(const float* __restrict__ w2,
                                                   unsigned short* __restrict__ w2p,
                                                   int tile, int t, char* lds) {
    const int e  = tile >> 7;
    const int k0 = ((tile >> 4) & 7) * 64;
    const int n0 = (tile & 15) * 64;
    unsigned short (*Tl)[72] = reinterpret_cast<unsigned short(*)[72]>(lds);
    const int kl = t >> 4, nl = (t & 15) * 4;
    const float* src = w2 + (size_t)e * (IMID * HID) + (size_t)k0 * 1024 + n0;
    #pragma unroll
    for (int p = 0; p < 4; ++p) {
        int k = kl + p * 16;
        f32x4 v = *reinterpret_cast<const f32x4*>(src + (size_t)k * 1024 + nl);
        uint2 wv; wv.x = pack2(v.x, v.y); wv.y = pack2(v.z, v.w);
        *reinterpret_cast<uint2*>(&Tl[k][nl]) = wv;
    }
    __syncthreads();
    const int nloc = t >> 2, kc = (t & 3) * 16;
    unsigned int v32[8];
    #pragma unroll
    for (int j = 0; j < 8; ++j)
        v32[j] = (unsigned int)Tl[kc + 2 * j][nloc] |
                 ((unsigned int)Tl[kc + 2 * j + 1][nloc] << 16);
    unsigned short* dst = w2p + (size_t)e * (HID * IMID) + (size_t)(n0 + nloc) * IMID + k0 + kc;
    uint4 o0 = {v32[0], v32[1], v32[2], v32[3]};
    uint4 o1 = {v32[4], v32[5], v32[6], v32[7]};
    *reinterpret_cast<uint4*>(dst)     = o0;
    *reinterpret_cast<uint4*>(dst + 8) = o1;
}

// ---- R10-proven gemm1 body: 128m x 256n' tile, BK=64, 4 waves, acc 4x8 ----
// Processes experts [ebase, ebase+32). bid in [0, 1024).
static __device__ __forceinline__ void gemm1_body(
    const unsigned short* __restrict__ xbf, const int* __restrict__ tpe,
    const unsigned short* __restrict__ w13p, unsigned short* __restrict__ hbuf,
    int ebase, int bid, int t, char* lds) {
    const int work = (bid & 7) * 128 + (bid >> 3);   // bijective over 1024
    const int e  = ebase + (work >> 5);
    const int nt = (work >> 3) & 3;
    const int mt = work & 7;
    const int lane = t & 63, w = t >> 6;

    int cnt = tpe[e]; if (cnt > CAP) cnt = CAP;
    const int m0 = mt * 128;
    if (m0 >= cnt) return;
    const int start = expert_start(tpe, e, lane);

    char* As = lds;            // [128 m][64k] (16 KB)
    char* Bs = lds + 16384;    // [256 n'][64k] (32 KB)
    const int wr = w >> 1, wc = w & 1;
    const int r = lane & 15, q = lane >> 4;

    f32x4 acc[4][8];
    const f32x4 z4 = {0.f, 0.f, 0.f, 0.f};
    #pragma unroll
    for (int i = 0; i < 4; ++i)
        #pragma unroll
        for (int j = 0; j < 8; ++j) acc[i][j] = z4;

    const int swb = ((lane & 7) ^ (lane >> 3)) << 4;
    const char* aP = (const char*)xbf;   // 2048 B rows
    const char* bP = (const char*)w13p + ((size_t)e << 21) + ((size_t)nt << 19);

    for (int kt = 0; kt < 16; ++kt) {
        __syncthreads();
        const int kb = kt * 128;
        #pragma unroll
        for (int i = 0; i < 4; ++i) {
            const int srow = w * 32 + i * 8 + (lane >> 3);
            long ar = (long)start + m0 + srow;
            if (ar > TTOK - 1) ar = TTOK - 1;
            gload16(aP + ar * 2048 + kb + swb, As + w * 4096 + i * 1024);
        }
        #pragma unroll
        for (int i = 0; i < 8; ++i) {
            const int srow = w * 64 + i * 8 + (lane >> 3);
            gload16(bP + (size_t)srow * 2048 + kb + swb, Bs + w * 8192 + i * 1024);
        }
        __syncthreads();
        #pragma unroll
        for (int kk = 0; kk < 2; ++kk) {
            bf16x8 af[4], bf[8];
            #pragma unroll
            for (int fm = 0; fm < 4; ++fm) {
                int row = (wr << 6) + (fm << 4) + r;
                af[fm] = *reinterpret_cast<const bf16x8*>(
                    As + row * 128 + ((kk * 64 + q * 16) ^ ((row & 7) << 4)));
            }
            #pragma unroll
            for (int fn = 0; fn < 8; ++fn) {
                int row = (wc << 7) + (fn << 4) + r;
                bf[fn] = *reinterpret_cast<const bf16x8*>(
                    Bs + row * 128 + ((kk * 64 + q * 16) ^ ((row & 7) << 4)));
            }
            #pragma unroll
            for (int fm = 0; fm < 4; ++fm)
                #pragma unroll
                for (int fn = 0; fn < 8; ++fn)
                    acc[fm][fn] = __builtin_amdgcn_mfma_f32_16x16x32_bf16(
                        af[fm], bf[fn], acc[fm][fn], 0, 0, 0);
        }
    }

    // SwiGLU: fn = c2*4 + isup*2 + fp; icol = (nt*4 + wc*2 + c2)*32 + fp*16 + r
    #pragma unroll
    for (int fm = 0; fm < 4; ++fm) {
        int mb = m0 + (wr << 6) + (fm << 4) + (q << 2);
        #pragma unroll
        for (int c2 = 0; c2 < 2; ++c2) {
            #pragma unroll
            for (int fp = 0; fp < 2; ++fp) {
                f32x4 g = acc[fm][c2 * 4 + fp];
                f32x4 u = acc[fm][c2 * 4 + 2 + fp];
                int icol = (nt * 4 + wc * 2 + c2) * 32 + fp * 16 + r;
                #pragma unroll
                for (int v = 0; v < 4; ++v) {
                    if (mb + v < cnt) {
                        float gv = g[v];
                        float sv = (gv / (1.f + __expf(-gv))) * u[v];
                        hbuf[(size_t)(start + mb + v) * IMID + icol] = f2bf_s(sv);
                    }
                }
            }
        }
    }
}

// ================= P1: x cvt (16384 blocks) + w13 cvt experts 0..31 (8192)
__global__ __launch_bounds__(256)
void phase1(const float* __restrict__ x, unsigned short* __restrict__ xbf,
            const float* __restrict__ w13, unsigned short* __restrict__ w13p) {
    __shared__ alignas(16) char lds[9216];
    const int bid = blockIdx.x;
    const int t   = threadIdx.x;
    if (bid < 16384) {
        size_t i = ((size_t)bid * 256 + t) * 8;
        f32x4 a = *reinterpret_cast<const f32x4*>(x + i);
        f32x4 b = *reinterpret_cast<const f32x4*>(x + i + 4);
        uint4 o;
        o.x = pack2(a.x, a.y); o.y = pack2(a.z, a.w);
        o.z = pack2(b.x, b.y); o.w = pack2(b.z, b.w);
        *reinterpret_cast<uint4*>(xbf + i) = o;
    } else {
        const int tile = bid - 16384;            // 0..8191
        const int e  = tile >> 8;                // 0..31
        const int k0 = ((tile >> 4) & 15) * 64;
        const int n0 = (tile & 15) * 64;
        w13_tile_cvt(w13, w13p, e, k0, n0, t, lds);
    }
}

// ================= P2: gemm1 experts 0..31 (1024 blocks) + w13 cvt e32..63
__global__ __launch_bounds__(256, 2)
void phase2(const unsigned short* __restrict__ xbf, const int* __restrict__ tpe,
            const unsigned short* __restrict__ w13p, unsigned short* __restrict__ hbuf,
            const float* __restrict__ w13) {
    __shared__ alignas(16) char lds[49152];
    const int bid = blockIdx.x;                  // 9216 blocks
    const int t   = threadIdx.x;
    if (bid < 1024) {
        gemm1_body(xbf, tpe, w13p, hbuf, 0, bid, t, lds);
    } else {
        const int tile = bid - 1024;             // 0..8191
        const int e  = 32 + (tile >> 8);         // 32..63
        const int k0 = ((tile >> 4) & 15) * 64;
        const int n0 = (tile & 15) * 64;
        w13_tile_cvt(w13, (unsigned short*)w13p, e, k0, n0, t, lds);
    }
}

// ================= P3: gemm1 experts 32..63 (1024 blocks) + w2 cvt (8192)
__global__ __launch_bounds__(256, 2)
void phase3(const unsigned short* __restrict__ xbf, const int* __restrict__ tpe,
            const unsigned short* __restrict__ w13p, unsigned short* __restrict__ hbuf,
            const float* __restrict__ w2, unsigned short* __restrict__ w2p) {
    __shared__ alignas(16) char lds[49152];
    const int bid = blockIdx.x;                  // 9216 blocks
    const int t   = threadIdx.x;
    if (bid < 1024) {
        gemm1_body(xbf, tpe, w13p, hbuf, 32, bid, t, lds);
    } else {
        w2_tile_cvt(w2, w2p, bid - 1024, t, lds);
    }
}

// ================= P4 (gemm2): hbuf[cnt,512] x w2p -> out fp32 [T,1024]
__global__ __launch_bounds__(256, 2)
void gemm2(const unsigned short* __restrict__ hbuf,
           const int* __restrict__ tpe,
           const unsigned short* __restrict__ w2p,
           float* __restrict__ out) {
    __shared__ alignas(16) char lds[49152];
    const int bid  = blockIdx.x;                 // 2048 blocks
    const int work = (bid & 7) * 256 + (bid >> 3);
    const int e  = work >> 5;
    const int nt = (work >> 3) & 3;
    const int mt = work & 7;

    const int t = threadIdx.x, lane = t & 63, w = t >> 6;
    int cnt = tpe[e]; if (cnt > CAP) cnt = CAP;
    const int m0 = mt * 128;
    if (m0 >= cnt) return;
    const int start = expert_start(tpe, e, lane);

    char* As = lds;
    char* Bs = lds + 16384;
    const int wr = w >> 1, wc = w & 1;
    const int r = lane & 15, q = lane >> 4;

    f32x4 acc[4][8];
    const f32x4 z4 = {0.f, 0.f, 0.f, 0.f};
    #pragma unroll
    for (int i = 0; i < 4; ++i)
        #pragma unroll
        for (int j = 0; j < 8; ++j) acc[i][j] = z4;

    const int swb = ((lane & 7) ^ (lane >> 3)) << 4;
    const char* aP = (const char*)hbuf;   // 1024 B rows
    const char* bP = (const char*)w2p + ((size_t)e << 20) + ((size_t)nt << 18);

    for (int kt = 0; kt < 8; ++kt) {
        __syncthreads();
        const int kb = kt * 128;
        #pragma unroll
        for (int i = 0; i < 4; ++i) {
            const int srow = w * 32 + i * 8 + (lane >> 3);
            long ar = (long)start + m0 + srow;
            if (ar > TTOK - 1) ar = TTOK - 1;
            gload16(aP + ar * 1024 + kb + swb, As + w * 4096 + i * 1024);
        }
        #pragma unroll
        for (int i = 0; i < 8; ++i) {
            const int srow = w * 64 + i * 8 + (lane >> 3);
            gload16(bP + (size_t)srow * 1024 + kb + swb, Bs + w * 8192 + i * 1024);
        }
        __syncthreads();
        #pragma unroll
        for (int kk = 0; kk < 2; ++kk) {
            bf16x8 af[4], bf[8];
            #pragma unroll
            for (int fm = 0; fm < 4; ++fm) {
                int row = (wr << 6) + (fm << 4) + r;
                af[fm] = *reinterpret_cast<const bf16x8*>(
                    As + row * 128 + ((kk * 64 + q * 16) ^ ((row & 7) << 4)));
            }
            #pragma unroll
            for (int fn = 0; fn < 8; ++fn) {
                int row = (wc << 7) + (fn << 4) + r;
                bf[fn] = *reinterpret_cast<const bf16x8*>(
                    Bs + row * 128 + ((kk * 64 + q * 16) ^ ((row & 7) << 4)));
            }
            #pragma unroll
            for (int fm = 0; fm < 4; ++fm)
                #pragma unroll
                for (int fn = 0; fn < 8; ++fn)
                    acc[fm][fn] = __builtin_amdgcn_mfma_f32_16x16x32_bf16(
                        af[fm], bf[fn], acc[fm][fn], 0, 0, 0);
        }
    }

    #pragma unroll
    for (int fm = 0; fm < 4; ++fm) {
        int mb = m0 + (wr << 6) + (fm << 4) + (q << 2);
        #pragma unroll
        for (int fn = 0; fn < 8; ++fn) {
            int ocol = (nt << 8) + (wc << 7) + (fn << 4) + r;
            #pragma unroll
            for (int v = 0; v < 4; ++v) {
                if (mb + v < cnt)
                    out[(size_t)(start + mb + v) * HID + ocol] = acc[fm][fn][v];
            }
        }
    }
}

extern "C" void kernel_launch(void* const* d_in, const int* in_sizes, int n_in,
                              void* d_out, int out_size, void* d_ws, size_t ws_size,
                              hipStream_t stream) {
    const float* x   = (const float*)d_in[0];
    const int*   tpe = (const int*)d_in[1];
    const float* w13 = (const float*)d_in[2];
    const float* w2  = (const float*)d_in[3];
    float* out = (float*)d_out;

    char* ws = (char*)d_ws;
    unsigned short* xbf  = (unsigned short*)(ws);                           // 67 MB
    unsigned short* hbuf = (unsigned short*)(ws + 67108864);                // 33.5 MB
    unsigned short* w13p = (unsigned short*)(ws + 67108864 + 33554432);     // 134 MB
    unsigned short* w2p  = (unsigned short*)(ws + 67108864 + 33554432 + 134217728); // 67 MB

    phase1<<<dim3(24576, 1, 1), dim3(256, 1, 1), 0, stream>>>(x, xbf, w13, w13p);
    phase2<<<dim3(9216, 1, 1), dim3(256, 1, 1), 0, stream>>>(xbf, tpe, w13p, hbuf, w13);
    phase3<<<dim3(9216, 1, 1), dim3(256, 1, 1), 0, stream>>>(xbf, tpe, w13p, hbuf, w2, w2p);
    gemm2 <<<dim3(2048, 1, 1), dim3(256, 1, 1), 0, stream>>>(hbuf, tpe, w2p, out);
}

// Round 13
// 282.856 us; speedup vs baseline: 1.1054x; 1.0091x over previous
//
#include <hip/hip_runtime.h>
#include <hip/hip_bf16.h>
#include <stdint.h>

#define NEXP 64
#define TTOK 32768
#define HID  1024
#define IMID 512
#define CAP  1024

typedef __bf16 bf16x8 __attribute__((ext_vector_type(8)));
typedef float  f32x4  __attribute__((ext_vector_type(4)));

static __device__ __forceinline__ unsigned int f2bf_u(float f) {
    __hip_bfloat16 h = __float2bfloat16(f);
    return (unsigned int)*reinterpret_cast<unsigned short*>(&h);
}
static __device__ __forceinline__ unsigned int pack2(float lo, float hi) {
    return f2bf_u(lo) | (f2bf_u(hi) << 16);
}
static __device__ __forceinline__ unsigned short f2bf_s(float f) {
    __hip_bfloat16 h = __float2bfloat16(f);
    return *reinterpret_cast<unsigned short*>(&h);
}

static __device__ __forceinline__ void gload16(const void* g, void* l) {
    __builtin_amdgcn_global_load_lds(
        (const __attribute__((address_space(1))) unsigned int*)g,
        (__attribute__((address_space(3))) unsigned int*)l,
        16, 0, 0);
}

// wave-parallel exclusive prefix: sum of tpe[i] for i < e
static __device__ __forceinline__ int expert_start(const int* tpe, int e, int lane) {
    int v = tpe[lane];
    int contrib = (lane < e) ? v : 0;
    #pragma unroll
    for (int off = 1; off < 64; off <<= 1)
        contrib += __shfl_xor(contrib, off, 64);
    return contrib;
}

// ---- R10-proven 64x64 transpose-convert bodies ----

// w13: fp32 [e][1024k][1024n] -> bf16 [e][np][1024k], np pairing 32-col granular
static __device__ __forceinline__ void w13_tile_cvt(const float* __restrict__ w13,
                                                    unsigned short* __restrict__ w13p,
                                                    int e, int k0, int n0, int t, char* lds) {
    unsigned short (*Tl)[72] = reinterpret_cast<unsigned short(*)[72]>(lds);  // 9216 B
    const int kl = t >> 4, nl = (t & 15) * 4;
    const float* src = w13 + ((size_t)e << 20) + (size_t)k0 * 1024 + n0;
    #pragma unroll
    for (int p = 0; p < 4; ++p) {
        int k = kl + p * 16;
        f32x4 v = *reinterpret_cast<const f32x4*>(src + (size_t)k * 1024 + nl);
        uint2 wv; wv.x = pack2(v.x, v.y); wv.y = pack2(v.z, v.w);
        *reinterpret_cast<uint2*>(&Tl[k][nl]) = wv;
    }
    __syncthreads();
    const int nloc = t >> 2, kc = (t & 3) * 16;
    const int n = n0 + nloc;
    const int icol = n & 511, isup = n >> 9;
    const int np = (icol >> 5) * 64 + isup * 32 + (icol & 31);
    unsigned int v32[8];
    #pragma unroll
    for (int j = 0; j < 8; ++j)
        v32[j] = (unsigned int)Tl[kc + 2 * j][nloc] |
                 ((unsigned int)Tl[kc + 2 * j + 1][nloc] << 16);
    unsigned short* dst = w13p + ((size_t)e << 20) + (size_t)np * 1024 + k0 + kc;
    uint4 o0 = {v32[0], v32[1], v32[2], v32[3]};
    uint4 o1 = {v32[4], v32[5], v32[6], v32[7]};
    *reinterpret_cast<uint4*>(dst)     = o0;
    *reinterpret_cast<uint4*>(dst + 8) = o1;
}

// w2: fp32 [e][512k][1024n] -> bf16 [e][n][512k]
static __device__ __forceinline__ void w2_tile_cvt(const float* __restrict__ w2,
                                                   unsigned short* __restrict__ w2p,
                                                   int tile, int t, char* lds) {
    const int e  = tile >> 7;
    const int k0 = ((tile >> 4) & 7) * 64;
    const int n0 = (tile & 15) * 64;
    unsigned short (*Tl)[72] = reinterpret_cast<unsigned short(*)[72]>(lds);
    const int kl = t >> 4, nl = (t & 15) * 4;
    const float* src = w2 + (size_t)e * (IMID * HID) + (size_t)k0 * 1024 + n0;
    #pragma unroll
    for (int p = 0; p < 4; ++p) {
        int k = kl + p * 16;
        f32x4 v = *reinterpret_cast<const f32x4*>(src + (size_t)k * 1024 + nl);
        uint2 wv; wv.x = pack2(v.x, v.y); wv.y = pack2(v.z, v.w);
        *reinterpret_cast<uint2*>(&Tl[k][nl]) = wv;
    }
    __syncthreads();
    const int nloc = t >> 2, kc = (t & 3) * 16;
    unsigned int v32[8];
    #pragma unroll
    for (int j = 0; j < 8; ++j)
        v32[j] = (unsigned int)Tl[kc + 2 * j][nloc] |
                 ((unsigned int)Tl[kc + 2 * j + 1][nloc] << 16);
    unsigned short* dst = w2p + (size_t)e * (HID * IMID) + (size_t)(n0 + nloc) * IMID + k0 + kc;
    uint4 o0 = {v32[0], v32[1], v32[2], v32[3]};
    uint4 o1 = {v32[4], v32[5], v32[6], v32[7]};
    *reinterpret_cast<uint4*>(dst)     = o0;
    *reinterpret_cast<uint4*>(dst + 8) = o1;
}

// ---- gemm1 body: 128m x 256n' tile, BK=64, 4 waves, acc 4x8.
// A: x fp32 read directly, in-loop cvt, reg-prefetched one kt ahead (T14).
// B: w13p bf16 via global_load_lds (both-sides swizzle).
static __device__ __forceinline__ void gemm1_body(
    const float* __restrict__ x, const int* __restrict__ tpe,
    const unsigned short* __restrict__ w13p, unsigned short* __restrict__ hbuf,
    int ebase, int bid, int t, char* lds) {
    const int work = (bid & 7) * 128 + (bid >> 3);   // bijective over 1024
    const int e  = ebase + (work >> 5);
    const int nt = (work >> 3) & 3;
    const int mt = work & 7;
    const int lane = t & 63, w = t >> 6;

    int cnt = tpe[e]; if (cnt > CAP) cnt = CAP;
    const int m0 = mt * 128;
    if (m0 >= cnt) return;
    const int start = expert_start(tpe, e, lane);

    char* As = lds;            // [128 m][64k] (16 KB), XOR-swizzled rows
    char* Bs = lds + 16384;    // [256 n'][64k] (32 KB), source-swizzled
    const int wr = w >> 1, wc = w & 1;
    const int r = lane & 15, q = lane >> 4;

    f32x4 acc[4][8];
    const f32x4 z4 = {0.f, 0.f, 0.f, 0.f};
    #pragma unroll
    for (int i = 0; i < 4; ++i)
        #pragma unroll
        for (int j = 0; j < 8; ++j) acc[i][j] = z4;

    const int swb = ((lane & 7) ^ (lane >> 3)) << 4;
    const char* bP = (const char*)w13p + ((size_t)e << 21) + ((size_t)nt << 19);

    // A staging geometry: per pass p (4 passes), row rr = p*32 + (t>>3),
    // thread covers 8 fp32 (kc = t&7), writes one swizzled b128.
    const int arow = t >> 3;          // 0..31
    const int akc  = t & 7;           // 0..7
    long arows[4];
    #pragma unroll
    for (int p = 0; p < 4; ++p) {
        long ar = (long)start + m0 + p * 32 + arow;
        if (ar > TTOK - 1) ar = TTOK - 1;
        arows[p] = ar;
    }

    f32x4 pa[8];
    #define LOADA(kt_)                                                          \
        _Pragma("unroll")                                                       \
        for (int p = 0; p < 4; ++p) {                                           \
            const float* sp = x + arows[p] * 1024 + (kt_) * 64 + akc * 8;       \
            pa[2 * p]     = *reinterpret_cast<const f32x4*>(sp);                \
            pa[2 * p + 1] = *reinterpret_cast<const f32x4*>(sp + 4);            \
        }
    #define WRITEA()                                                            \
        _Pragma("unroll")                                                       \
        for (int p = 0; p < 4; ++p) {                                           \
            int rr = p * 32 + arow;                                             \
            uint4 o;                                                            \
            o.x = pack2(pa[2 * p].x,     pa[2 * p].y);                          \
            o.y = pack2(pa[2 * p].z,     pa[2 * p].w);                          \
            o.z = pack2(pa[2 * p + 1].x, pa[2 * p + 1].y);                      \
            o.w = pack2(pa[2 * p + 1].z, pa[2 * p + 1].w);                      \
            *reinterpret_cast<uint4*>(As + rr * 128 +                           \
                ((akc * 16) ^ ((rr & 7) << 4))) = o;                            \
        }

    LOADA(0);
    for (int kt = 0; kt < 16; ++kt) {
        __syncthreads();                    // LDS free from previous compute
        const int kb = kt * 128;
        #pragma unroll
        for (int i = 0; i < 8; ++i) {
            const int srow = w * 64 + i * 8 + (lane >> 3);
            gload16(bP + (size_t)srow * 2048 + kb + swb, Bs + w * 8192 + i * 1024);
        }
        WRITEA();                           // cvt + LDS write of A(kt)
        __syncthreads();                    // stage done (drains B + A writes)
        if (kt < 15) { LOADA(kt + 1); }     // hidden under compute
        #pragma unroll
        for (int kk = 0; kk < 2; ++kk) {
            bf16x8 af[4], bf[8];
            #pragma unroll
            for (int fm = 0; fm < 4; ++fm) {
                int row = (wr << 6) + (fm << 4) + r;
                af[fm] = *reinterpret_cast<const bf16x8*>(
                    As + row * 128 + ((kk * 64 + q * 16) ^ ((row & 7) << 4)));
            }
            #pragma unroll
            for (int fn = 0; fn < 8; ++fn) {
                int row = (wc << 7) + (fn << 4) + r;
                bf[fn] = *reinterpret_cast<const bf16x8*>(
                    Bs + row * 128 + ((kk * 64 + q * 16) ^ ((row & 7) << 4)));
            }
            #pragma unroll
            for (int fm = 0; fm < 4; ++fm)
                #pragma unroll
                for (int fn = 0; fn < 8; ++fn)
                    acc[fm][fn] = __builtin_amdgcn_mfma_f32_16x16x32_bf16(
                        af[fm], bf[fn], acc[fm][fn], 0, 0, 0);
        }
    }
    #undef LOADA
    #undef WRITEA

    // SwiGLU: fn = c2*4 + isup*2 + fp; icol = (nt*4 + wc*2 + c2)*32 + fp*16 + r
    #pragma unroll
    for (int fm = 0; fm < 4; ++fm) {
        int mb = m0 + (wr << 6) + (fm << 4) + (q << 2);
        #pragma unroll
        for (int c2 = 0; c2 < 2; ++c2) {
            #pragma unroll
            for (int fp = 0; fp < 2; ++fp) {
                f32x4 g = acc[fm][c2 * 4 + fp];
                f32x4 u = acc[fm][c2 * 4 + 2 + fp];
                int icol = (nt * 4 + wc * 2 + c2) * 32 + fp * 16 + r;
                #pragma unroll
                for (int v = 0; v < 4; ++v) {
                    if (mb + v < cnt) {
                        float gv = g[v];
                        float sv = (gv / (1.f + __expf(-gv))) * u[v];
                        hbuf[(size_t)(start + mb + v) * IMID + icol] = f2bf_s(sv);
                    }
                }
            }
        }
    }
}

// ================= P1: w13 cvt experts 0..31 (8192 blocks)
__global__ __launch_bounds__(256)
void phase1(const float* __restrict__ w13, unsigned short* __restrict__ w13p) {
    __shared__ alignas(16) char lds[9216];
    const int bid = blockIdx.x;
    const int t   = threadIdx.x;
    const int e  = bid >> 8;                 // 0..31
    const int k0 = ((bid >> 4) & 15) * 64;
    const int n0 = (bid & 15) * 64;
    w13_tile_cvt(w13, w13p, e, k0, n0, t, lds);
}

// ================= P2: gemm1 experts 0..31 (1024 blocks) + w13 cvt e32..63
__global__ __launch_bounds__(256, 2)
void phase2(const float* __restrict__ x, const int* __restrict__ tpe,
            const unsigned short* __restrict__ w13p, unsigned short* __restrict__ hbuf,
            const float* __restrict__ w13) {
    __shared__ alignas(16) char lds[49152];
    const int bid = blockIdx.x;                  // 9216 blocks
    const int t   = threadIdx.x;
    if (bid < 1024) {
        gemm1_body(x, tpe, w13p, hbuf, 0, bid, t, lds);
    } else {
        const int tile = bid - 1024;             // 0..8191
        const int e  = 32 + (tile >> 8);         // 32..63
        const int k0 = ((tile >> 4) & 15) * 64;
        const int n0 = (tile & 15) * 64;
        w13_tile_cvt(w13, (unsigned short*)w13p, e, k0, n0, t, lds);
    }
}

// ================= P3: gemm1 experts 32..63 (1024 blocks) + w2 cvt (8192)
__global__ __launch_bounds__(256, 2)
void phase3(const float* __restrict__ x, const int* __restrict__ tpe,
            const unsigned short* __restrict__ w13p, unsigned short* __restrict__ hbuf,
            const float* __restrict__ w2, unsigned short* __restrict__ w2p) {
    __shared__ alignas(16) char lds[49152];
    const int bid = blockIdx.x;                  // 9216 blocks
    const int t   = threadIdx.x;
    if (bid < 1024) {
        gemm1_body(x, tpe, w13p, hbuf, 32, bid, t, lds);
    } else {
        w2_tile_cvt(w2, w2p, bid - 1024, t, lds);
    }
}

// ================= P4 (gemm2): hbuf[cnt,512] x w2p -> out fp32 [T,1024]
__global__ __launch_bounds__(256, 2)
void gemm2(const unsigned short* __restrict__ hbuf,
           const int* __restrict__ tpe,
           const unsigned short* __restrict__ w2p,
           float* __restrict__ out) {
    __shared__ alignas(16) char lds[49152];
    const int bid  = blockIdx.x;                 // 2048 blocks
    const int work = (bid & 7) * 256 + (bid >> 3);
    const int e  = work >> 5;
    const int nt = (work >> 3) & 3;
    const int mt = work & 7;

    const int t = threadIdx.x, lane = t & 63, w = t >> 6;
    int cnt = tpe[e]; if (cnt > CAP) cnt = CAP;
    const int m0 = mt * 128;
    if (m0 >= cnt) return;
    const int start = expert_start(tpe, e, lane);

    char* As = lds;
    char* Bs = lds + 16384;
    const int wr = w >> 1, wc = w & 1;
    const int r = lane & 15, q = lane >> 4;

    f32x4 acc[4][8];
    const f32x4 z4 = {0.f, 0.f, 0.f, 0.f};
    #pragma unroll
    for (int i = 0; i < 4; ++i)
        #pragma unroll
        for (int j = 0; j < 8; ++j) acc[i][j] = z4;

    const int swb = ((lane & 7) ^ (lane >> 3)) << 4;
    const char* aP = (const char*)hbuf;   // 1024 B rows
    const char* bP = (const char*)w2p + ((size_t)e << 20) + ((size_t)nt << 18);

    for (int kt = 0; kt < 8; ++kt) {
        __syncthreads();
        const int kb = kt * 128;
        #pragma unroll
        for (int i = 0; i < 4; ++i) {
            const int srow = w * 32 + i * 8 + (lane >> 3);
            long ar = (long)start + m0 + srow;
            if (ar > TTOK - 1) ar = TTOK - 1;
            gload16(aP + ar * 1024 + kb + swb, As + w * 4096 + i * 1024);
        }
        #pragma unroll
        for (int i = 0; i < 8; ++i) {
            const int srow = w * 64 + i * 8 + (lane >> 3);
            gload16(bP + (size_t)srow * 1024 + kb + swb, Bs + w * 8192 + i * 1024);
        }
        __syncthreads();
        #pragma unroll
        for (int kk = 0; kk < 2; ++kk) {
            bf16x8 af[4], bf[8];
            #pragma unroll
            for (int fm = 0; fm < 4; ++fm) {
                int row = (wr << 6) + (fm << 4) + r;
                af[fm] = *reinterpret_cast<const bf16x8*>(
                    As + row * 128 + ((kk * 64 + q * 16) ^ ((row & 7) << 4)));
            }
            #pragma unroll
            for (int fn = 0; fn < 8; ++fn) {
                int row = (wc << 7) + (fn << 4) + r;
                bf[fn] = *reinterpret_cast<const bf16x8*>(
                    Bs + row * 128 + ((kk * 64 + q * 16) ^ ((row & 7) << 4)));
            }
            #pragma unroll
            for (int fm = 0; fm < 4; ++fm)
                #pragma unroll
                for (int fn = 0; fn < 8; ++fn)
                    acc[fm][fn] = __builtin_amdgcn_mfma_f32_16x16x32_bf16(
                        af[fm], bf[fn], acc[fm][fn], 0, 0, 0);
        }
    }

    #pragma unroll
    for (int fm = 0; fm < 4; ++fm) {
        int mb = m0 + (wr << 6) + (fm << 4) + (q << 2);
        #pragma unroll
        for (int fn = 0; fn < 8; ++fn) {
            int ocol = (nt << 8) + (wc << 7) + (fn << 4) + r;
            #pragma unroll
            for (int v = 0; v < 4; ++v) {
                if (mb + v < cnt)
                    out[(size_t)(start + mb + v) * HID + ocol] = acc[fm][fn][v];
            }
        }
    }
}

extern "C" void kernel_launch(void* const* d_in, const int* in_sizes, int n_in,
                              void* d_out, int out_size, void* d_ws, size_t ws_size,
                              hipStream_t stream) {
    const float* x   = (const float*)d_in[0];
    const int*   tpe = (const int*)d_in[1];
    const float* w13 = (const float*)d_in[2];
    const float* w2  = (const float*)d_in[3];
    float* out = (float*)d_out;

    char* ws = (char*)d_ws;
    unsigned short* hbuf = (unsigned short*)(ws);                           // 33.5 MB
    unsigned short* w13p = (unsigned short*)(ws + 33554432);                // 134 MB
    unsigned short* w2p  = (unsigned short*)(ws + 33554432 + 134217728);    // 67 MB

    phase1<<<dim3(8192, 1, 1), dim3(256, 1, 1), 0, stream>>>(w13, w13p);
    phase2<<<dim3(9216, 1, 1), dim3(256, 1, 1), 0, stream>>>(x, tpe, w13p, hbuf, w13);
    phase3<<<dim3(9216, 1, 1), dim3(256, 1, 1), 0, stream>>>(x, tpe, w13p, hbuf, w2, w2p);
    gemm2 <<<dim3(2048, 1, 1), dim3(256, 1, 1), 0, stream>>>(hbuf, tpe, w2p, out);
}